// Round 3
// baseline (2341.674 us; speedup 1.0000x reference)
//
#include <hip/hip_runtime.h>
#include <hip/hip_bf16.h>
#include <math.h>

#define B_ 32
#define S_ 64
#define T_ 64
#define V_ 32000
#define E_ 512
#define H_ 1024

typedef __attribute__((ext_vector_type(8))) short short8;
typedef __attribute__((ext_vector_type(4))) float f32x4;

static __device__ __forceinline__ unsigned short f2bf(float f) {
  union { float f; unsigned u; } c; c.f = f;
  unsigned r = (c.u + 0x7fffu + ((c.u >> 16) & 1u)) >> 16;  // RNE
  return (unsigned short)r;
}

// ---------- gather embedding rows (fp32, exact) ----------
__global__ __launch_bounds__(128)
void gather_f32(const int* __restrict__ idx, const float* __restrict__ emb,
                float* __restrict__ dst) {
  int r = blockIdx.x;
  int tid = threadIdx.x;
  int tok = idx[r];
  float4 v = *(const float4*)(emb + (size_t)tok * E_ + tid * 4);
  *(float4*)(dst + (size_t)r * E_ + tid * 4) = v;
}

// ---------- f64-accumulate GEMM: C[M,N](f64) = A[M,K](f32) @ B[K,N](f32) + bias ----------
// BM=BN=64, BK=32; 256 threads (16x16), 4x4 outputs/thread. f32xf32 products
// are exact in f64; accumulation error ~1e-13 -> trajectory-exact x.
__global__ __launch_bounds__(256)
void dgemm_bias(const float* __restrict__ A, const float* __restrict__ B,
                const float* __restrict__ bias, double* __restrict__ C,
                int M, int N, int K) {
  __shared__ float As[32][65];  // [k][m], padded
  __shared__ float Bs[32][64];  // [k][n]
  const int nbm = M >> 6;
  const int bm = blockIdx.x % nbm;
  const int bn = blockIdx.x / nbm;
  const int tid = threadIdx.x;
  const int tr = tid >> 4, tc = tid & 15;
  double acc[4][4] = {};

  for (int kt = 0; kt < K; kt += 32) {
    {
      int arow = tid >> 3, acol = (tid & 7) * 4;
#pragma unroll
      for (int p = 0; p < 2; ++p) {
        int r = arow + p * 32;
        float4 v = *(const float4*)(A + (size_t)(bm * 64 + r) * K + kt + acol);
        As[acol + 0][r] = v.x; As[acol + 1][r] = v.y;
        As[acol + 2][r] = v.z; As[acol + 3][r] = v.w;
      }
      int brow = tid >> 4, bcol = (tid & 15) * 4;
#pragma unroll
      for (int p = 0; p < 2; ++p) {
        int r = brow + p * 16;
        float4 v = *(const float4*)(B + (size_t)(kt + r) * N + bn * 64 + bcol);
        *(float4*)(&Bs[r][bcol]) = v;
      }
    }
    __syncthreads();
#pragma unroll
    for (int k = 0; k < 32; ++k) {
      double a[4], b[4];
#pragma unroll
      for (int i = 0; i < 4; ++i) a[i] = (double)As[k][tr * 4 + i];
#pragma unroll
      for (int j = 0; j < 4; ++j) b[j] = (double)Bs[k][tc * 4 + j];
#pragma unroll
      for (int i = 0; i < 4; ++i)
#pragma unroll
        for (int j = 0; j < 4; ++j) acc[i][j] = fma(a[i], b[j], acc[i][j]);
    }
    __syncthreads();
  }
#pragma unroll
  for (int i = 0; i < 4; ++i) {
    int gm = bm * 64 + tr * 4 + i;
    int gn = bn * 64 + tc * 4;
#pragma unroll
    for (int j = 0; j < 4; ++j)
      C[(size_t)gm * N + gn + j] = acc[i][j] + (double)bias[gn + j];
  }
}

// ---------- transpose fp32 [K][N] -> bf16 [N][K] ----------
__global__ __launch_bounds__(256)
void transpose_bf16(const float* __restrict__ W, unsigned short* __restrict__ WT,
                    int K, int N) {
  __shared__ float t[64][65];
  int k0 = blockIdx.x * 64;
  int n0 = blockIdx.y * 64;
  int tid = threadIdx.x;
  int r = tid >> 4, c4 = tid & 15;
#pragma unroll
  for (int i = 0; i < 4; ++i) {
    int row = r + i * 16;
    float4 v = *(const float4*)(W + (size_t)(k0 + row) * N + n0 + c4 * 4);
    t[row][c4 * 4 + 0] = v.x; t[row][c4 * 4 + 1] = v.y;
    t[row][c4 * 4 + 2] = v.z; t[row][c4 * 4 + 3] = v.w;
  }
  __syncthreads();
#pragma unroll
  for (int i = 0; i < 4; ++i) {
    int n = r + i * 16;
    ushort4 o;
    o.x = f2bf(t[c4 * 4 + 0][n]); o.y = f2bf(t[c4 * 4 + 1][n]);
    o.z = f2bf(t[c4 * 4 + 2][n]); o.w = f2bf(t[c4 * 4 + 3][n]);
    *(ushort4*)(WT + (size_t)(n0 + n) * K + k0 + c4 * 4) = o;
  }
}

// ---------- bf16 MFMA GEMM: C[M,N] = A[M,K] * BT[N,K]^T + bias ----------
// 128x128 tile, BK=64, 4 waves (2x2), each wave 64x64 via 4x4 16x16x32 frags.
// LDS XOR swizzle (16B chunk ^= row&7) -> conflict-free ds_read_b128.
// Row gm = t*B + b is written to out[b][t][:] (B=32 hardcoded).
__global__ __launch_bounds__(256)
void gemm_bt_swap(const unsigned short* __restrict__ A, const unsigned short* __restrict__ BT,
                  const float* __restrict__ bias, float* __restrict__ C,
                  int M, int N, int K) {
  __shared__ unsigned short As[128 * 64];
  __shared__ unsigned short Bs[128 * 64];
  const int nbm = M >> 7;
  const int bm = blockIdx.x % nbm;
  const int bn = blockIdx.x / nbm;
  const int tid = threadIdx.x;
  const int lane = tid & 63;
  const int wr = (tid >> 6) >> 1;
  const int wc = (tid >> 6) & 1;

  f32x4 acc[4][4] = {};

  for (int kt = 0; kt < K; kt += 64) {
#pragma unroll
    for (int i = 0; i < 4; ++i) {
      int c = i * 256 + tid;
      int row = c >> 3, col8 = c & 7;
      int sw = col8 ^ (row & 7);
      short8 av = *(const short8*)(A + (size_t)(bm * 128 + row) * K + kt + col8 * 8);
      short8 bv = *(const short8*)(BT + (size_t)(bn * 128 + row) * K + kt + col8 * 8);
      *(short8*)(As + row * 64 + sw * 8) = av;
      *(short8*)(Bs + row * 64 + sw * 8) = bv;
    }
    __syncthreads();
#pragma unroll
    for (int kk = 0; kk < 64; kk += 32) {
      int kc = (kk + ((lane >> 4) << 3)) >> 3;
      short8 af[4], bfr[4];
#pragma unroll
      for (int mi = 0; mi < 4; ++mi) {
        int row = wr * 64 + mi * 16 + (lane & 15);
        af[mi] = *(const short8*)(As + row * 64 + ((kc ^ (row & 7)) << 3));
      }
#pragma unroll
      for (int ni = 0; ni < 4; ++ni) {
        int row = wc * 64 + ni * 16 + (lane & 15);
        bfr[ni] = *(const short8*)(Bs + row * 64 + ((kc ^ (row & 7)) << 3));
      }
#pragma unroll
      for (int mi = 0; mi < 4; ++mi)
#pragma unroll
        for (int ni = 0; ni < 4; ++ni)
          acc[mi][ni] = __builtin_amdgcn_mfma_f32_16x16x32_bf16(
              af[mi], bfr[ni], acc[mi][ni], 0, 0, 0);
    }
    __syncthreads();
  }

  const int cq = (lane >> 4) << 2;  // C/D: row = (lane>>4)*4 + q, col = lane&15
  const int cn = lane & 15;
#pragma unroll
  for (int mi = 0; mi < 4; ++mi) {
#pragma unroll
    for (int ni = 0; ni < 4; ++ni) {
      int gn = bn * 128 + wc * 64 + ni * 16 + cn;
      float bv = bias[gn];
#pragma unroll
      for (int q = 0; q < 4; ++q) {
        int gm = bm * 128 + wr * 64 + mi * 16 + cq + q;
        int b = gm & (B_ - 1);
        int t = gm >> 5;
        C[((size_t)b * T_ + t) * N + gn] = acc[mi][ni][q] + bv;
      }
    }
  }
}

// ---------- one RNN step (f64): h_out = tanh(x + h_in @ Whh + bhh) ----------
// grid 256 = 32 b * 8 jtiles(128 cols); block 256 = 128 j * 2 K-halves.
// h kept in f64; Whh read as f32 (exact in f64 products).
__global__ __launch_bounds__(256)
void rnn_step_f64(const double* __restrict__ h_in, const double* __restrict__ x,
                  int x_stride, const float* __restrict__ Whh,
                  const float* __restrict__ bhh, double* __restrict__ h_out,
                  unsigned short* __restrict__ hs_bf16) {
  __shared__ double hl[1024];
  __shared__ double ps[256];
  const int b = blockIdx.x >> 3;
  const int jt = blockIdx.x & 7;
  const int tid = threadIdx.x;
  {
    const double* srcp = h_in + b * 1024 + tid * 4;
    double2 v0 = *(const double2*)(srcp);
    double2 v1 = *(const double2*)(srcp + 2);
    *(double2*)(hl + tid * 4) = v0;
    *(double2*)(hl + tid * 4 + 2) = v1;
  }
  __syncthreads();
  const int jj = tid & 127;
  const int eh = tid >> 7;
  const int j = jt * 128 + jj;
  const float* W = Whh + (size_t)eh * 512 * 1024 + j;
  const double* hp = hl + eh * 512;
  double a0 = 0., a1 = 0., a2 = 0., a3 = 0.;
#pragma unroll 4
  for (int e = 0; e < 512; e += 4) {
    double2 h01 = *(const double2*)(hp + e);
    double2 h23 = *(const double2*)(hp + e + 2);
    a0 = fma(h01.x, (double)W[(size_t)(e + 0) * 1024], a0);
    a1 = fma(h01.y, (double)W[(size_t)(e + 1) * 1024], a1);
    a2 = fma(h23.x, (double)W[(size_t)(e + 2) * 1024], a2);
    a3 = fma(h23.y, (double)W[(size_t)(e + 3) * 1024], a3);
  }
  ps[tid] = (a0 + a1) + (a2 + a3);
  __syncthreads();
  if (tid < 128) {
    double v = ps[tid] + ps[tid + 128] + x[(size_t)b * x_stride + j] + (double)bhh[j];
    double h = tanh(v);
    h_out[b * 1024 + j] = h;
    if (hs_bf16) hs_bf16[b * 1024 + j] = f2bf((float)h);
  }
}

// ---------- in-place log-softmax over rows of 32000 ----------
__global__ __launch_bounds__(256)
void log_softmax_rows(float* __restrict__ out) {
  float* row = out + (size_t)blockIdx.x * V_;
  const int tid = threadIdx.x;
  float m = -INFINITY, s = 0.f;
  for (int i = tid; i < V_ / 4; i += 256) {
    float4 v = *(const float4*)(row + i * 4);
    float mx = fmaxf(fmaxf(v.x, v.y), fmaxf(v.z, v.w));
    if (mx > m) { s *= __expf(m - mx); m = mx; }
    s += __expf(v.x - m) + __expf(v.y - m) + __expf(v.z - m) + __expf(v.w - m);
  }
#pragma unroll
  for (int o = 32; o; o >>= 1) {
    float mo = __shfl_xor(m, o);
    float so = __shfl_xor(s, o);
    float mn = fmaxf(m, mo);
    s = s * __expf(m - mn) + so * __expf(mo - mn);
    m = mn;
  }
  __shared__ float wm[4], wsv[4];
  int wv = tid >> 6;
  if ((tid & 63) == 0) { wm[wv] = m; wsv[wv] = s; }
  __syncthreads();
  float M = fmaxf(fmaxf(wm[0], wm[1]), fmaxf(wm[2], wm[3]));
  float Ssum = wsv[0] * __expf(wm[0] - M) + wsv[1] * __expf(wm[1] - M) +
               wsv[2] * __expf(wm[2] - M) + wsv[3] * __expf(wm[3] - M);
  float L = M + logf(Ssum);
  for (int i = tid; i < V_ / 4; i += 256) {
    float4 v = *(const float4*)(row + i * 4);
    v.x -= L; v.y -= L; v.z -= L; v.w -= L;
    *(float4*)(row + i * 4) = v;
  }
}

extern "C" void kernel_launch(void* const* d_in, const int* in_sizes, int n_in,
                              void* d_out, int out_size, void* d_ws, size_t ws_size,
                              hipStream_t stream) {
  const int*   src  = (const int*)  d_in[0];
  const int*   tgt  = (const int*)  d_in[1];
  const float* encE = (const float*)d_in[2];
  const float* decE = (const float*)d_in[3];
  const float* WihE = (const float*)d_in[4];
  const float* bihE = (const float*)d_in[5];
  const float* WhhE = (const float*)d_in[6];
  const float* bhhE = (const float*)d_in[7];
  const float* WihD = (const float*)d_in[8];
  const float* bihD = (const float*)d_in[9];
  const float* WhhD = (const float*)d_in[10];
  const float* bhhD = (const float*)d_in[11];
  const float* Wout = (const float*)d_in[12];
  const float* bout = (const float*)d_in[13];
  float* out = (float*)d_out;

  char* w = (char*)d_ws;
  double* x_e = (double*)w;                    w += (size_t)2048 * 1024 * 8;
  double* x_d = (double*)w;                    w += (size_t)2048 * 1024 * 8;
  double* h0  = (double*)w;                    w += 32 * 1024 * 8;
  double* h1  = (double*)w;                    w += 32 * 1024 * 8;
  float* AembF = (float*)w;                    w += (size_t)2048 * 512 * 4;
  unsigned short* hsb   = (unsigned short*)w;  w += (size_t)2048 * 1024 * 2;
  unsigned short* WoutT = (unsigned short*)w;  w += (size_t)V_ * 1024 * 2;

  // Encoder input projection (f64-exact): x_e = enc_emb[src] @ Wih_e + bih_e
  gather_f32<<<B_ * S_, 128, 0, stream>>>(src, encE, AembF);
  dgemm_bias<<<(2048 / 64) * (H_ / 64), 256, 0, stream>>>(AembF, WihE, bihE, x_e,
                                                          2048, H_, E_);
  // Decoder input projection (f64-exact)
  gather_f32<<<B_ * T_, 128, 0, stream>>>(tgt, decE, AembF);
  dgemm_bias<<<(2048 / 64) * (H_ / 64), 256, 0, stream>>>(AembF, WihD, bihD, x_d,
                                                          2048, H_, E_);

  // Encoder scan (f64 recurrence)
  hipMemsetAsync(h0, 0, 32 * 1024 * 8, stream);
  double* hc = h0;
  double* hn = h1;
  for (int s = 0; s < S_; ++s) {
    rnn_step_f64<<<256, 256, 0, stream>>>(hc, x_e + (size_t)s * H_, S_ * H_, WhhE,
                                          bhhE, hn, (unsigned short*)nullptr);
    double* tmp = hc; hc = hn; hn = tmp;
  }
  // Decoder scan (f64), emitting hs rows (bf16, non-feedback) at row t*B + b
  for (int t = 0; t < T_; ++t) {
    rnn_step_f64<<<256, 256, 0, stream>>>(hc, x_d + (size_t)t * H_, T_ * H_, WhhD,
                                          bhhD, hn, hsb + (size_t)t * B_ * H_);
    double* tmp = hc; hc = hn; hn = tmp;
  }

  // Logits: out[b][t][:] = hs[t*B+b] @ Wout + bout  (bf16 MFMA, raw logits)
  transpose_bf16<<<dim3(H_ / 64, V_ / 64), 256, 0, stream>>>(Wout, WoutT, H_, V_);
  gemm_bt_swap<<<(2048 / 128) * (V_ / 128), 256, 0, stream>>>(hsb, WoutT, bout, out,
                                                              2048, V_, H_);
  // In-place log-softmax
  log_softmax_rows<<<B_ * T_, 256, 0, stream>>>(out);
}

// Round 4
// 2288.378 us; speedup vs baseline: 1.0233x; 1.0233x over previous
//
#include <hip/hip_runtime.h>
#include <hip/hip_bf16.h>
#include <math.h>

#define B_ 32
#define S_ 64
#define T_ 64
#define V_ 32000
#define E_ 512
#define H_ 1024

typedef __attribute__((ext_vector_type(8))) short short8;
typedef __attribute__((ext_vector_type(4))) float f32x4;

static __device__ __forceinline__ unsigned short f2bf(float f) {
  union { float f; unsigned u; } c; c.f = f;
  unsigned r = (c.u + 0x7fffu + ((c.u >> 16) & 1u)) >> 16;  // RNE
  return (unsigned short)r;
}

// ---------- gather embedding rows (fp32, exact) ----------
__global__ __launch_bounds__(128)
void gather_f32(const int* __restrict__ idx, const float* __restrict__ emb,
                float* __restrict__ dst) {
  int r = blockIdx.x;
  int tid = threadIdx.x;
  int tok = idx[r];
  float4 v = *(const float4*)(emb + (size_t)tok * E_ + tid * 4);
  *(float4*)(dst + (size_t)r * E_ + tid * 4) = v;
}

// ---------- f64-accumulate GEMM: C[M,N](f32) = A[M,K](f32) @ B[K,N](f32) + bias ----------
// f32xf32 products exact in f64; accumulation error ~1e-13 -> trajectory-exact x.
__global__ __launch_bounds__(256)
void dgemm_bias(const float* __restrict__ A, const float* __restrict__ B,
                const float* __restrict__ bias, float* __restrict__ C,
                int M, int N, int K) {
  __shared__ float As[32][65];  // [k][m], padded
  __shared__ float Bs[32][64];  // [k][n]
  const int nbm = M >> 6;
  const int bm = blockIdx.x % nbm;
  const int bn = blockIdx.x / nbm;
  const int tid = threadIdx.x;
  const int tr = tid >> 4, tc = tid & 15;
  double acc[4][4] = {};

  for (int kt = 0; kt < K; kt += 32) {
    {
      int arow = tid >> 3, acol = (tid & 7) * 4;
#pragma unroll
      for (int p = 0; p < 2; ++p) {
        int r = arow + p * 32;
        float4 v = *(const float4*)(A + (size_t)(bm * 64 + r) * K + kt + acol);
        As[acol + 0][r] = v.x; As[acol + 1][r] = v.y;
        As[acol + 2][r] = v.z; As[acol + 3][r] = v.w;
      }
      int brow = tid >> 4, bcol = (tid & 15) * 4;
#pragma unroll
      for (int p = 0; p < 2; ++p) {
        int r = brow + p * 16;
        float4 v = *(const float4*)(B + (size_t)(kt + r) * N + bn * 64 + bcol);
        *(float4*)(&Bs[r][bcol]) = v;
      }
    }
    __syncthreads();
#pragma unroll
    for (int k = 0; k < 32; ++k) {
      double a[4], b[4];
#pragma unroll
      for (int i = 0; i < 4; ++i) a[i] = (double)As[k][tr * 4 + i];
#pragma unroll
      for (int j = 0; j < 4; ++j) b[j] = (double)Bs[k][tc * 4 + j];
#pragma unroll
      for (int i = 0; i < 4; ++i)
#pragma unroll
        for (int j = 0; j < 4; ++j) acc[i][j] = fma(a[i], b[j], acc[i][j]);
    }
    __syncthreads();
  }
#pragma unroll
  for (int i = 0; i < 4; ++i) {
    int gm = bm * 64 + tr * 4 + i;
    int gn = bn * 64 + tc * 4;
    float4 o;
    o.x = (float)(acc[i][0] + (double)bias[gn + 0]);
    o.y = (float)(acc[i][1] + (double)bias[gn + 1]);
    o.z = (float)(acc[i][2] + (double)bias[gn + 2]);
    o.w = (float)(acc[i][3] + (double)bias[gn + 3]);
    *(float4*)(C + (size_t)gm * N + gn) = o;
  }
}

// ---------- transpose fp32 [K][N] -> fp32 [N][K] ----------
__global__ __launch_bounds__(256)
void transpose_f32(const float* __restrict__ W, float* __restrict__ WT,
                   int K, int N) {
  __shared__ float t[64][65];
  int k0 = blockIdx.x * 64;
  int n0 = blockIdx.y * 64;
  int tid = threadIdx.x;
  int r = tid >> 4, c4 = tid & 15;
#pragma unroll
  for (int i = 0; i < 4; ++i) {
    int row = r + i * 16;
    float4 v = *(const float4*)(W + (size_t)(k0 + row) * N + n0 + c4 * 4);
    t[row][c4 * 4 + 0] = v.x; t[row][c4 * 4 + 1] = v.y;
    t[row][c4 * 4 + 2] = v.z; t[row][c4 * 4 + 3] = v.w;
  }
  __syncthreads();
#pragma unroll
  for (int i = 0; i < 4; ++i) {
    int n = r + i * 16;
    float4 o;
    o.x = t[c4 * 4 + 0][n]; o.y = t[c4 * 4 + 1][n];
    o.z = t[c4 * 4 + 2][n]; o.w = t[c4 * 4 + 3][n];
    *(float4*)(WT + (size_t)(n0 + n) * K + k0 + c4 * 4) = o;
  }
}

// ---------- transpose fp32 [K][N] -> bf16 [N][K] ----------
__global__ __launch_bounds__(256)
void transpose_bf16(const float* __restrict__ W, unsigned short* __restrict__ WT,
                    int K, int N) {
  __shared__ float t[64][65];
  int k0 = blockIdx.x * 64;
  int n0 = blockIdx.y * 64;
  int tid = threadIdx.x;
  int r = tid >> 4, c4 = tid & 15;
#pragma unroll
  for (int i = 0; i < 4; ++i) {
    int row = r + i * 16;
    float4 v = *(const float4*)(W + (size_t)(k0 + row) * N + n0 + c4 * 4);
    t[row][c4 * 4 + 0] = v.x; t[row][c4 * 4 + 1] = v.y;
    t[row][c4 * 4 + 2] = v.z; t[row][c4 * 4 + 3] = v.w;
  }
  __syncthreads();
#pragma unroll
  for (int i = 0; i < 4; ++i) {
    int n = r + i * 16;
    ushort4 o;
    o.x = f2bf(t[c4 * 4 + 0][n]); o.y = f2bf(t[c4 * 4 + 1][n]);
    o.z = f2bf(t[c4 * 4 + 2][n]); o.w = f2bf(t[c4 * 4 + 3][n]);
    *(ushort4*)(WT + (size_t)(n0 + n) * K + k0 + c4 * 4) = o;
  }
}

// ---------- bf16 MFMA GEMM: C[M,N] = A[M,K] * BT[N,K]^T + bias ----------
// 128x128 tile, BK=64, 4 waves (2x2), 4x4 16x16x32 frags/wave.
// LDS XOR swizzle -> conflict-free ds_read_b128. XCD-aware block swizzle (T1).
// Row gm = t*B + b is written to out[b][t][:] (B=32).
__global__ __launch_bounds__(256)
void gemm_bt_swap(const unsigned short* __restrict__ A, const unsigned short* __restrict__ BT,
                  const float* __restrict__ bias, float* __restrict__ C,
                  int M, int N, int K) {
  __shared__ unsigned short As[128 * 64];
  __shared__ unsigned short Bs[128 * 64];
  const int nbm = M >> 7;
  // XCD swizzle: gridDim.x % 8 == 0; each XCD gets a contiguous bn-range.
  int idx = blockIdx.x;
  const int cpx = gridDim.x >> 3;
  idx = (idx & 7) * cpx + (idx >> 3);
  const int bm = idx % nbm;
  const int bn = idx / nbm;
  const int tid = threadIdx.x;
  const int lane = tid & 63;
  const int wr = (tid >> 6) >> 1;
  const int wc = (tid >> 6) & 1;

  f32x4 acc[4][4] = {};

  for (int kt = 0; kt < K; kt += 64) {
#pragma unroll
    for (int i = 0; i < 4; ++i) {
      int c = i * 256 + tid;
      int row = c >> 3, col8 = c & 7;
      int sw = col8 ^ (row & 7);
      short8 av = *(const short8*)(A + (size_t)(bm * 128 + row) * K + kt + col8 * 8);
      short8 bv = *(const short8*)(BT + (size_t)(bn * 128 + row) * K + kt + col8 * 8);
      *(short8*)(As + row * 64 + sw * 8) = av;
      *(short8*)(Bs + row * 64 + sw * 8) = bv;
    }
    __syncthreads();
#pragma unroll
    for (int kk = 0; kk < 64; kk += 32) {
      int kc = (kk + ((lane >> 4) << 3)) >> 3;
      short8 af[4], bfr[4];
#pragma unroll
      for (int mi = 0; mi < 4; ++mi) {
        int row = wr * 64 + mi * 16 + (lane & 15);
        af[mi] = *(const short8*)(As + row * 64 + ((kc ^ (row & 7)) << 3));
      }
#pragma unroll
      for (int ni = 0; ni < 4; ++ni) {
        int row = wc * 64 + ni * 16 + (lane & 15);
        bfr[ni] = *(const short8*)(Bs + row * 64 + ((kc ^ (row & 7)) << 3));
      }
#pragma unroll
      for (int mi = 0; mi < 4; ++mi)
#pragma unroll
        for (int ni = 0; ni < 4; ++ni)
          acc[mi][ni] = __builtin_amdgcn_mfma_f32_16x16x32_bf16(
              af[mi], bfr[ni], acc[mi][ni], 0, 0, 0);
    }
    __syncthreads();
  }

  const int cq = (lane >> 4) << 2;  // C/D: row = (lane>>4)*4 + q, col = lane&15
  const int cn = lane & 15;
#pragma unroll
  for (int mi = 0; mi < 4; ++mi) {
#pragma unroll
    for (int ni = 0; ni < 4; ++ni) {
      int gn = bn * 128 + wc * 64 + ni * 16 + cn;
      float bv = bias[gn];
#pragma unroll
      for (int q = 0; q < 4; ++q) {
        int gm = bm * 128 + wr * 64 + mi * 16 + cq + q;
        int b = gm & (B_ - 1);
        int t = gm >> 5;
        C[((size_t)b * T_ + t) * N + gn] = acc[mi][ni][q] + bv;
      }
    }
  }
}

// ---------- one RNN step: h_out = tanh(x + h_in @ Whh + bhh) ----------
// j-partition x all-batch: grid 512 = 256 jgroups(4 cols) x 2 bhalves(16 rows).
// LDS: h 16x1024 f32 (XOR-swizzled by b) + WhhT slice 4x1024 (swizzled by j).
// f64 accumulate (4-acc chain) + q-split (k mod 4) + shfl reduce + f64 tanh.
__global__ __launch_bounds__(256)
void rnn_scan_step(const float* __restrict__ h_in, const float* __restrict__ x,
                   int s, const float* __restrict__ WT,
                   const float* __restrict__ bhh, float* __restrict__ h_out,
                   unsigned short* __restrict__ hs_bf16) {
  __shared__ float hl[16 * 1024];  // 64 KB
  __shared__ float wl[4 * 1024];   // 16 KB
  const int g = blockIdx.x;
  const int jbase = (g >> 1) * 4;
  const int bbase = (g & 1) * 16;
  const int tid = threadIdx.x;

  {  // stage h rows [bbase, bbase+16) -> LDS, swizzled
    const float4* src = (const float4*)(h_in + bbase * 1024);
#pragma unroll
    for (int p = 0; p < 16; ++p) {
      int i = tid + p * 256;          // float4 index, 4096 total
      int row = i >> 8;               // 256 float4 per row
      int k0 = (i & 255) << 2;
      float4 v = src[i];
      *(float4*)(hl + row * 1024 + (k0 ^ ((row & 7) << 2))) = v;
    }
    // stage WhhT rows [jbase, jbase+4) -> LDS, swizzled
    const float4* wsrc = (const float4*)(WT + (size_t)jbase * 1024);
#pragma unroll
    for (int p = 0; p < 4; ++p) {
      int i = tid + p * 256;          // 1024 float4
      int row = i >> 8;
      int k0 = (i & 255) << 2;
      float4 v = wsrc[i];
      *(float4*)(wl + row * 1024 + (k0 ^ (row << 2))) = v;
    }
  }
  __syncthreads();

  const int b = tid >> 4;
  const int j = (tid >> 2) & 3;
  const int q = tid & 3;
  const float* hb = hl + b * 1024;
  const float* wj = wl + j * 1024;
  const int swb = (b & 7) << 2;
  const int swj = j << 2;
  double a0 = 0., a1 = 0., a2 = 0., a3 = 0.;
#pragma unroll 4
  for (int kk = 0; kk < 256; kk += 4) {
    int k0 = (kk << 2) + q;
    a0 = fma((double)hb[(k0 + 0) ^ swb], (double)wj[(k0 + 0) ^ swj], a0);
    a1 = fma((double)hb[(k0 + 4) ^ swb], (double)wj[(k0 + 4) ^ swj], a1);
    a2 = fma((double)hb[(k0 + 8) ^ swb], (double)wj[(k0 + 8) ^ swj], a2);
    a3 = fma((double)hb[(k0 + 12) ^ swb], (double)wj[(k0 + 12) ^ swj], a3);
  }
  double acc = (a0 + a1) + (a2 + a3);
  acc += __shfl_xor(acc, 1);
  acc += __shfl_xor(acc, 2);
  if (q == 0) {
    int gb = bbase + b, gj = jbase + j;
    double v = acc + (double)x[((size_t)gb * 64 + s) * 1024 + gj] + (double)bhh[gj];
    double h = tanh(v);
    h_out[gb * 1024 + gj] = (float)h;
    if (hs_bf16) hs_bf16[(size_t)s * (B_ * H_) + gb * 1024 + gj] = f2bf((float)h);
  }
}

// ---------- in-place log-softmax over rows of 32000 ----------
__global__ __launch_bounds__(256)
void log_softmax_rows(float* __restrict__ out) {
  float* row = out + (size_t)blockIdx.x * V_;
  const int tid = threadIdx.x;
  float m = -INFINITY, s = 0.f;
  for (int i = tid; i < V_ / 4; i += 256) {
    float4 v = *(const float4*)(row + i * 4);
    float mx = fmaxf(fmaxf(v.x, v.y), fmaxf(v.z, v.w));
    if (mx > m) { s *= __expf(m - mx); m = mx; }
    s += __expf(v.x - m) + __expf(v.y - m) + __expf(v.z - m) + __expf(v.w - m);
  }
#pragma unroll
  for (int o = 32; o; o >>= 1) {
    float mo = __shfl_xor(m, o);
    float so = __shfl_xor(s, o);
    float mn = fmaxf(m, mo);
    s = s * __expf(m - mn) + so * __expf(mo - mn);
    m = mn;
  }
  __shared__ float wm[4], wsv[4];
  int wv = tid >> 6;
  if ((tid & 63) == 0) { wm[wv] = m; wsv[wv] = s; }
  __syncthreads();
  float M = fmaxf(fmaxf(wm[0], wm[1]), fmaxf(wm[2], wm[3]));
  float Ssum = wsv[0] * __expf(wm[0] - M) + wsv[1] * __expf(wm[1] - M) +
               wsv[2] * __expf(wm[2] - M) + wsv[3] * __expf(wm[3] - M);
  float L = M + logf(Ssum);
  for (int i = tid; i < V_ / 4; i += 256) {
    float4 v = *(const float4*)(row + i * 4);
    v.x -= L; v.y -= L; v.z -= L; v.w -= L;
    *(float4*)(row + i * 4) = v;
  }
}

extern "C" void kernel_launch(void* const* d_in, const int* in_sizes, int n_in,
                              void* d_out, int out_size, void* d_ws, size_t ws_size,
                              hipStream_t stream) {
  const int*   src  = (const int*)  d_in[0];
  const int*   tgt  = (const int*)  d_in[1];
  const float* encE = (const float*)d_in[2];
  const float* decE = (const float*)d_in[3];
  const float* WihE = (const float*)d_in[4];
  const float* bihE = (const float*)d_in[5];
  const float* WhhE = (const float*)d_in[6];
  const float* bhhE = (const float*)d_in[7];
  const float* WihD = (const float*)d_in[8];
  const float* bihD = (const float*)d_in[9];
  const float* WhhD = (const float*)d_in[10];
  const float* bhhD = (const float*)d_in[11];
  const float* Wout = (const float*)d_in[12];
  const float* bout = (const float*)d_in[13];
  float* out = (float*)d_out;

  char* w = (char*)d_ws;
  float* x_e = (float*)w;                      w += (size_t)2048 * 1024 * 4;
  float* x_d = (float*)w;                      w += (size_t)2048 * 1024 * 4;
  float* h0  = (float*)w;                      w += 32 * 1024 * 4;
  float* h1  = (float*)w;                      w += 32 * 1024 * 4;
  float* WhhTe = (float*)w;                    w += (size_t)1024 * 1024 * 4;
  float* WhhTd = (float*)w;                    w += (size_t)1024 * 1024 * 4;
  float* AembF = (float*)w;                    w += (size_t)2048 * 512 * 4;
  unsigned short* hsb   = (unsigned short*)w;  w += (size_t)2048 * 1024 * 2;
  unsigned short* WoutT = (unsigned short*)w;  w += (size_t)V_ * 1024 * 2;

  // Input projections (f64-exact accumulate, f32 storage)
  gather_f32<<<B_ * S_, 128, 0, stream>>>(src, encE, AembF);
  dgemm_bias<<<(2048 / 64) * (H_ / 64), 256, 0, stream>>>(AembF, WihE, bihE, x_e,
                                                          2048, H_, E_);
  gather_f32<<<B_ * T_, 128, 0, stream>>>(tgt, decE, AembF);
  dgemm_bias<<<(2048 / 64) * (H_ / 64), 256, 0, stream>>>(AembF, WihD, bihD, x_d,
                                                          2048, H_, E_);

  // Pre-transpose recurrence weights: WhhT[j][k] (coalesced slice loads)
  transpose_f32<<<dim3(H_ / 64, H_ / 64), 256, 0, stream>>>(WhhE, WhhTe, H_, H_);
  transpose_f32<<<dim3(H_ / 64, H_ / 64), 256, 0, stream>>>(WhhD, WhhTd, H_, H_);

  // Encoder scan
  hipMemsetAsync(h0, 0, 32 * 1024 * 4, stream);
  float* hc = h0;
  float* hn = h1;
  for (int s = 0; s < S_; ++s) {
    rnn_scan_step<<<512, 256, 0, stream>>>(hc, x_e, s, WhhTe, bhhE, hn,
                                           (unsigned short*)nullptr);
    float* tmp = hc; hc = hn; hn = tmp;
  }
  // Decoder scan, emitting hs rows (bf16, non-feedback) at row t*B + b
  for (int t = 0; t < T_; ++t) {
    rnn_scan_step<<<512, 256, 0, stream>>>(hc, x_d, t, WhhTd, bhhD, hn, hsb);
    float* tmp = hc; hc = hn; hn = tmp;
  }

  // Logits: out[b][t][:] = hs[t*B+b] @ Wout + bout  (bf16 MFMA, raw logits)
  transpose_bf16<<<dim3(H_ / 64, V_ / 64), 256, 0, stream>>>(Wout, WoutT, H_, V_);
  gemm_bt_swap<<<(2048 / 128) * (V_ / 128), 256, 0, stream>>>(hsb, WoutT, bout, out,
                                                              2048, V_, H_);
  // In-place log-softmax
  log_softmax_rows<<<B_ * T_, 256, 0, stream>>>(out);
}

// Round 5
// 2135.804 us; speedup vs baseline: 1.0964x; 1.0714x over previous
//
#include <hip/hip_runtime.h>
#include <hip/hip_bf16.h>
#include <math.h>

#define B_ 32
#define S_ 64
#define T_ 64
#define V_ 32000
#define E_ 512
#define H_ 1024

typedef __attribute__((ext_vector_type(8))) short short8;
typedef __attribute__((ext_vector_type(4))) float f32x4;

static __device__ __forceinline__ unsigned short f2bf(float f) {
  union { float f; unsigned u; } c; c.f = f;
  unsigned r = (c.u + 0x7fffu + ((c.u >> 16) & 1u)) >> 16;  // RNE
  return (unsigned short)r;
}

// ---------- gather embedding rows (fp32, exact) ----------
__global__ __launch_bounds__(128)
void gather_f32(const int* __restrict__ idx, const float* __restrict__ emb,
                float* __restrict__ dst) {
  int r = blockIdx.x;
  int tid = threadIdx.x;
  int tok = idx[r];
  float4 v = *(const float4*)(emb + (size_t)tok * E_ + tid * 4);
  *(float4*)(dst + (size_t)r * E_ + tid * 4) = v;
}

// ---------- f64-accumulate GEMM: C[M,N](f32) = A[M,K](f32) @ B[K,N](f32) + bias ----------
__global__ __launch_bounds__(256)
void dgemm_bias(const float* __restrict__ A, const float* __restrict__ B,
                const float* __restrict__ bias, float* __restrict__ C,
                int M, int N, int K) {
  __shared__ float As[32][65];  // [k][m], padded
  __shared__ float Bs[32][64];  // [k][n]
  const int nbm = M >> 6;
  const int bm = blockIdx.x % nbm;
  const int bn = blockIdx.x / nbm;
  const int tid = threadIdx.x;
  const int tr = tid >> 4, tc = tid & 15;
  double acc[4][4] = {};

  for (int kt = 0; kt < K; kt += 32) {
    {
      int arow = tid >> 3, acol = (tid & 7) * 4;
#pragma unroll
      for (int p = 0; p < 2; ++p) {
        int r = arow + p * 32;
        float4 v = *(const float4*)(A + (size_t)(bm * 64 + r) * K + kt + acol);
        As[acol + 0][r] = v.x; As[acol + 1][r] = v.y;
        As[acol + 2][r] = v.z; As[acol + 3][r] = v.w;
      }
      int brow = tid >> 4, bcol = (tid & 15) * 4;
#pragma unroll
      for (int p = 0; p < 2; ++p) {
        int r = brow + p * 16;
        float4 v = *(const float4*)(B + (size_t)(kt + r) * N + bn * 64 + bcol);
        *(float4*)(&Bs[r][bcol]) = v;
      }
    }
    __syncthreads();
#pragma unroll
    for (int k = 0; k < 32; ++k) {
      double a[4], b[4];
#pragma unroll
      for (int i = 0; i < 4; ++i) a[i] = (double)As[k][tr * 4 + i];
#pragma unroll
      for (int j = 0; j < 4; ++j) b[j] = (double)Bs[k][tc * 4 + j];
#pragma unroll
      for (int i = 0; i < 4; ++i)
#pragma unroll
        for (int j = 0; j < 4; ++j) acc[i][j] = fma(a[i], b[j], acc[i][j]);
    }
    __syncthreads();
  }
#pragma unroll
  for (int i = 0; i < 4; ++i) {
    int gm = bm * 64 + tr * 4 + i;
    int gn = bn * 64 + tc * 4;
    float4 o;
    o.x = (float)(acc[i][0] + (double)bias[gn + 0]);
    o.y = (float)(acc[i][1] + (double)bias[gn + 1]);
    o.z = (float)(acc[i][2] + (double)bias[gn + 2]);
    o.w = (float)(acc[i][3] + (double)bias[gn + 3]);
    *(float4*)(C + (size_t)gm * N + gn) = o;
  }
}

// ---------- transpose fp32 [K][N] -> fp32 [N][K] ----------
__global__ __launch_bounds__(256)
void transpose_f32(const float* __restrict__ W, float* __restrict__ WT,
                   int K, int N) {
  __shared__ float t[64][65];
  int k0 = blockIdx.x * 64;
  int n0 = blockIdx.y * 64;
  int tid = threadIdx.x;
  int r = tid >> 4, c4 = tid & 15;
#pragma unroll
  for (int i = 0; i < 4; ++i) {
    int row = r + i * 16;
    float4 v = *(const float4*)(W + (size_t)(k0 + row) * N + n0 + c4 * 4);
    t[row][c4 * 4 + 0] = v.x; t[row][c4 * 4 + 1] = v.y;
    t[row][c4 * 4 + 2] = v.z; t[row][c4 * 4 + 3] = v.w;
  }
  __syncthreads();
#pragma unroll
  for (int i = 0; i < 4; ++i) {
    int n = r + i * 16;
    float4 o;
    o.x = t[c4 * 4 + 0][n]; o.y = t[c4 * 4 + 1][n];
    o.z = t[c4 * 4 + 2][n]; o.w = t[c4 * 4 + 3][n];
    *(float4*)(WT + (size_t)(n0 + n) * K + k0 + c4 * 4) = o;
  }
}

// ---------- transpose fp32 [K][N] -> bf16 [N][K] ----------
__global__ __launch_bounds__(256)
void transpose_bf16(const float* __restrict__ W, unsigned short* __restrict__ WT,
                    int K, int N) {
  __shared__ float t[64][65];
  int k0 = blockIdx.x * 64;
  int n0 = blockIdx.y * 64;
  int tid = threadIdx.x;
  int r = tid >> 4, c4 = tid & 15;
#pragma unroll
  for (int i = 0; i < 4; ++i) {
    int row = r + i * 16;
    float4 v = *(const float4*)(W + (size_t)(k0 + row) * N + n0 + c4 * 4);
    t[row][c4 * 4 + 0] = v.x; t[row][c4 * 4 + 1] = v.y;
    t[row][c4 * 4 + 2] = v.z; t[row][c4 * 4 + 3] = v.w;
  }
  __syncthreads();
#pragma unroll
  for (int i = 0; i < 4; ++i) {
    int n = r + i * 16;
    ushort4 o;
    o.x = f2bf(t[c4 * 4 + 0][n]); o.y = f2bf(t[c4 * 4 + 1][n]);
    o.z = f2bf(t[c4 * 4 + 2][n]); o.w = f2bf(t[c4 * 4 + 3][n]);
    *(ushort4*)(WT + (size_t)(n0 + n) * K + k0 + c4 * 4) = o;
  }
}

// ---------- bf16 MFMA GEMM: C[M,N] = A[M,K] * BT[N,K]^T + bias ----------
__global__ __launch_bounds__(256)
void gemm_bt_swap(const unsigned short* __restrict__ A, const unsigned short* __restrict__ BT,
                  const float* __restrict__ bias, float* __restrict__ C,
                  int M, int N, int K) {
  __shared__ unsigned short As[128 * 64];
  __shared__ unsigned short Bs[128 * 64];
  const int nbm = M >> 7;
  int idx = blockIdx.x;
  const int cpx = gridDim.x >> 3;
  idx = (idx & 7) * cpx + (idx >> 3);
  const int bm = idx % nbm;
  const int bn = idx / nbm;
  const int tid = threadIdx.x;
  const int lane = tid & 63;
  const int wr = (tid >> 6) >> 1;
  const int wc = (tid >> 6) & 1;

  f32x4 acc[4][4] = {};

  for (int kt = 0; kt < K; kt += 64) {
#pragma unroll
    for (int i = 0; i < 4; ++i) {
      int c = i * 256 + tid;
      int row = c >> 3, col8 = c & 7;
      int sw = col8 ^ (row & 7);
      short8 av = *(const short8*)(A + (size_t)(bm * 128 + row) * K + kt + col8 * 8);
      short8 bv = *(const short8*)(BT + (size_t)(bn * 128 + row) * K + kt + col8 * 8);
      *(short8*)(As + row * 64 + sw * 8) = av;
      *(short8*)(Bs + row * 64 + sw * 8) = bv;
    }
    __syncthreads();
#pragma unroll
    for (int kk = 0; kk < 64; kk += 32) {
      int kc = (kk + ((lane >> 4) << 3)) >> 3;
      short8 af[4], bfr[4];
#pragma unroll
      for (int mi = 0; mi < 4; ++mi) {
        int row = wr * 64 + mi * 16 + (lane & 15);
        af[mi] = *(const short8*)(As + row * 64 + ((kc ^ (row & 7)) << 3));
      }
#pragma unroll
      for (int ni = 0; ni < 4; ++ni) {
        int row = wc * 64 + ni * 16 + (lane & 15);
        bfr[ni] = *(const short8*)(Bs + row * 64 + ((kc ^ (row & 7)) << 3));
      }
#pragma unroll
      for (int mi = 0; mi < 4; ++mi)
#pragma unroll
        for (int ni = 0; ni < 4; ++ni)
          acc[mi][ni] = __builtin_amdgcn_mfma_f32_16x16x32_bf16(
              af[mi], bfr[ni], acc[mi][ni], 0, 0, 0);
    }
    __syncthreads();
  }

  const int cq = (lane >> 4) << 2;
  const int cn = lane & 15;
#pragma unroll
  for (int mi = 0; mi < 4; ++mi) {
#pragma unroll
    for (int ni = 0; ni < 4; ++ni) {
      int gn = bn * 128 + wc * 64 + ni * 16 + cn;
      float bv = bias[gn];
#pragma unroll
      for (int q = 0; q < 4; ++q) {
        int gm = bm * 128 + wr * 64 + mi * 16 + cq + q;
        int b = gm & (B_ - 1);
        int t = gm >> 5;
        C[((size_t)b * T_ + t) * N + gn] = acc[mi][ni][q] + bv;
      }
    }
  }
}

// ---------- RNN step, register-tiled: h_out = tanh(x + h_in @ Whh + bhh) ----------
// Grid 256 blocks (4 j-cols each), 512 threads = 8 btiles(4b) x 64 ksplit.
// LDS: full h[32][1024] f32 (128 KB) + WhhT slice [4][1024] (16 KB), both
// granule(16B)-XOR swizzled -> conflict-free ds_read_b128.
// Rb=4 x Rj=4 register tile: 8 b128 reads per 16 f64 FMAs (64 MACs).
// 6-step f64 shfl_xor butterfly reduces the 64-way k-split.
__global__ __launch_bounds__(512)
void rnn_scan_step2(const float* __restrict__ h_in, const float* __restrict__ x,
                    int s, const float* __restrict__ WT,
                    const float* __restrict__ bhh, float* __restrict__ h_out,
                    unsigned short* __restrict__ hs_bf16) {
  __shared__ float hl[32 * 1024];  // 128 KB
  __shared__ float wl[4 * 1024];   // 16 KB
  const int jbase = blockIdx.x * 4;
  const int tid = threadIdx.x;

  {  // stage h: 8192 float4, coalesced, granule-XOR by b
    const float4* hsrc = (const float4*)h_in;
#pragma unroll
    for (int p = 0; p < 16; ++p) {
      int i = tid + p * 512;
      int b = i >> 8;
      int g = i & 255;
      float4 v = hsrc[i];
      *(float4*)(hl + b * 1024 + ((g ^ (b & 7)) << 2)) = v;
    }
    // stage WhhT rows [jbase, jbase+4): 1024 float4, granule-XOR by j
    const float4* wsrc = (const float4*)(WT + (size_t)jbase * 1024);
#pragma unroll
    for (int p = 0; p < 2; ++p) {
      int i = tid + p * 512;
      int j = i >> 8;
      int g = i & 255;
      float4 v = wsrc[i];
      *(float4*)(wl + j * 1024 + ((g ^ j) << 2)) = v;
    }
  }
  __syncthreads();

  const int bt = tid >> 6;   // btile: b = bt*4 + bi
  const int ks = tid & 63;   // k-split lane
  double acc[4][4];
#pragma unroll
  for (int bi = 0; bi < 4; ++bi)
#pragma unroll
    for (int ji = 0; ji < 4; ++ji) acc[bi][ji] = 0.;

#pragma unroll
  for (int i = 0; i < 4; ++i) {
    int g = ks + 64 * i;  // 16B granule index (k = 4g..4g+3)
    float4 hv[4], wv[4];
#pragma unroll
    for (int bi = 0; bi < 4; ++bi) {
      int b = bt * 4 + bi;
      hv[bi] = *(const float4*)(hl + b * 1024 + ((g ^ (b & 7)) << 2));
    }
#pragma unroll
    for (int ji = 0; ji < 4; ++ji)
      wv[ji] = *(const float4*)(wl + ji * 1024 + ((g ^ ji) << 2));
#pragma unroll
    for (int bi = 0; bi < 4; ++bi)
#pragma unroll
      for (int ji = 0; ji < 4; ++ji) {
        acc[bi][ji] = fma((double)hv[bi].x, (double)wv[ji].x, acc[bi][ji]);
        acc[bi][ji] = fma((double)hv[bi].y, (double)wv[ji].y, acc[bi][ji]);
        acc[bi][ji] = fma((double)hv[bi].z, (double)wv[ji].z, acc[bi][ji]);
        acc[bi][ji] = fma((double)hv[bi].w, (double)wv[ji].w, acc[bi][ji]);
      }
  }

  // 64-lane f64 butterfly allreduce of the 16 accumulators
#pragma unroll
  for (int o = 32; o; o >>= 1)
#pragma unroll
    for (int bi = 0; bi < 4; ++bi)
#pragma unroll
      for (int ji = 0; ji < 4; ++ji)
        acc[bi][ji] += __shfl_xor(acc[bi][ji], o);

  if (ks < 16) {
    int bi = ks >> 2, ji = ks & 3;
    int gb = bt * 4 + bi, gj = jbase + ji;
    double v = acc[bi][ji] + (double)x[((size_t)gb * 64 + s) * 1024 + gj] +
               (double)bhh[gj];
    double h = tanh(v);
    h_out[gb * 1024 + gj] = (float)h;
    if (hs_bf16) hs_bf16[(size_t)s * (B_ * H_) + gb * 1024 + gj] = f2bf((float)h);
  }
}

// ---------- in-place log-softmax over rows of 32000 ----------
__global__ __launch_bounds__(256)
void log_softmax_rows(float* __restrict__ out) {
  float* row = out + (size_t)blockIdx.x * V_;
  const int tid = threadIdx.x;
  float m = -INFINITY, s = 0.f;
  for (int i = tid; i < V_ / 4; i += 256) {
    float4 v = *(const float4*)(row + i * 4);
    float mx = fmaxf(fmaxf(v.x, v.y), fmaxf(v.z, v.w));
    if (mx > m) { s *= __expf(m - mx); m = mx; }
    s += __expf(v.x - m) + __expf(v.y - m) + __expf(v.z - m) + __expf(v.w - m);
  }
#pragma unroll
  for (int o = 32; o; o >>= 1) {
    float mo = __shfl_xor(m, o);
    float so = __shfl_xor(s, o);
    float mn = fmaxf(m, mo);
    s = s * __expf(m - mn) + so * __expf(mo - mn);
    m = mn;
  }
  __shared__ float wm[4], wsv[4];
  int wv = tid >> 6;
  if ((tid & 63) == 0) { wm[wv] = m; wsv[wv] = s; }
  __syncthreads();
  float M = fmaxf(fmaxf(wm[0], wm[1]), fmaxf(wm[2], wm[3]));
  float Ssum = wsv[0] * __expf(wm[0] - M) + wsv[1] * __expf(wm[1] - M) +
               wsv[2] * __expf(wm[2] - M) + wsv[3] * __expf(wm[3] - M);
  float L = M + logf(Ssum);
  for (int i = tid; i < V_ / 4; i += 256) {
    float4 v = *(const float4*)(row + i * 4);
    v.x -= L; v.y -= L; v.z -= L; v.w -= L;
    *(float4*)(row + i * 4) = v;
  }
}

extern "C" void kernel_launch(void* const* d_in, const int* in_sizes, int n_in,
                              void* d_out, int out_size, void* d_ws, size_t ws_size,
                              hipStream_t stream) {
  const int*   src  = (const int*)  d_in[0];
  const int*   tgt  = (const int*)  d_in[1];
  const float* encE = (const float*)d_in[2];
  const float* decE = (const float*)d_in[3];
  const float* WihE = (const float*)d_in[4];
  const float* bihE = (const float*)d_in[5];
  const float* WhhE = (const float*)d_in[6];
  const float* bhhE = (const float*)d_in[7];
  const float* WihD = (const float*)d_in[8];
  const float* bihD = (const float*)d_in[9];
  const float* WhhD = (const float*)d_in[10];
  const float* bhhD = (const float*)d_in[11];
  const float* Wout = (const float*)d_in[12];
  const float* bout = (const float*)d_in[13];
  float* out = (float*)d_out;

  char* w = (char*)d_ws;
  float* x_e = (float*)w;                      w += (size_t)2048 * 1024 * 4;
  float* x_d = (float*)w;                      w += (size_t)2048 * 1024 * 4;
  float* h0  = (float*)w;                      w += 32 * 1024 * 4;
  float* h1  = (float*)w;                      w += 32 * 1024 * 4;
  float* WhhTe = (float*)w;                    w += (size_t)1024 * 1024 * 4;
  float* WhhTd = (float*)w;                    w += (size_t)1024 * 1024 * 4;
  float* AembF = (float*)w;                    w += (size_t)2048 * 512 * 4;
  unsigned short* hsb   = (unsigned short*)w;  w += (size_t)2048 * 1024 * 2;
  unsigned short* WoutT = (unsigned short*)w;  w += (size_t)V_ * 1024 * 2;

  // Input projections (f64-exact accumulate, f32 storage)
  gather_f32<<<B_ * S_, 128, 0, stream>>>(src, encE, AembF);
  dgemm_bias<<<(2048 / 64) * (H_ / 64), 256, 0, stream>>>(AembF, WihE, bihE, x_e,
                                                          2048, H_, E_);
  gather_f32<<<B_ * T_, 128, 0, stream>>>(tgt, decE, AembF);
  dgemm_bias<<<(2048 / 64) * (H_ / 64), 256, 0, stream>>>(AembF, WihD, bihD, x_d,
                                                          2048, H_, E_);

  // Pre-transpose recurrence weights: WhhT[j][k]
  transpose_f32<<<dim3(H_ / 64, H_ / 64), 256, 0, stream>>>(WhhE, WhhTe, H_, H_);
  transpose_f32<<<dim3(H_ / 64, H_ / 64), 256, 0, stream>>>(WhhD, WhhTd, H_, H_);

  // Encoder scan
  hipMemsetAsync(h0, 0, 32 * 1024 * 4, stream);
  float* hc = h0;
  float* hn = h1;
  for (int s = 0; s < S_; ++s) {
    rnn_scan_step2<<<256, 512, 0, stream>>>(hc, x_e, s, WhhTe, bhhE, hn,
                                            (unsigned short*)nullptr);
    float* tmp = hc; hc = hn; hn = tmp;
  }
  // Decoder scan, emitting hs rows (bf16, non-feedback) at row t*B + b
  for (int t = 0; t < T_; ++t) {
    rnn_scan_step2<<<256, 512, 0, stream>>>(hc, x_d, t, WhhTd, bhhD, hn, hsb);
    float* tmp = hc; hc = hn; hn = tmp;
  }

  // Logits: out[b][t][:] = hs[t*B+b] @ Wout + bout  (bf16 MFMA, raw logits)
  transpose_bf16<<<dim3(H_ / 64, V_ / 64), 256, 0, stream>>>(Wout, WoutT, H_, V_);
  gemm_bt_swap<<<(2048 / 128) * (V_ / 128), 256, 0, stream>>>(hsb, WoutT, bout, out,
                                                              2048, V_, H_);
  // In-place log-softmax
  log_softmax_rows<<<B_ * T_, 256, 0, stream>>>(out);
}

// Round 6
// 1355.836 us; speedup vs baseline: 1.7271x; 1.5753x over previous
//
#include <hip/hip_runtime.h>
#include <hip/hip_bf16.h>
#include <math.h>

#define B_ 32
#define S_ 64
#define T_ 64
#define V_ 32000
#define E_ 512
#define H_ 1024

typedef __attribute__((ext_vector_type(8))) short short8;
typedef __attribute__((ext_vector_type(4))) float f32x4;

static __device__ __forceinline__ unsigned short f2bf(float f) {
  union { float f; unsigned u; } c; c.f = f;
  unsigned r = (c.u + 0x7fffu + ((c.u >> 16) & 1u)) >> 16;  // RNE
  return (unsigned short)r;
}

// ---------- gather embedding rows (fp32, exact) ----------
__global__ __launch_bounds__(128)
void gather_f32(const int* __restrict__ idx, const float* __restrict__ emb,
                float* __restrict__ dst) {
  int r = blockIdx.x;
  int tid = threadIdx.x;
  int tok = idx[r];
  float4 v = *(const float4*)(emb + (size_t)tok * E_ + tid * 4);
  *(float4*)(dst + (size_t)r * E_ + tid * 4) = v;
}

// ---------- f64-accumulate GEMM: C[M,N](f32) = A[M,K](f32) @ B[K,N](f32) + bias ----------
__global__ __launch_bounds__(256)
void dgemm_bias(const float* __restrict__ A, const float* __restrict__ B,
                const float* __restrict__ bias, float* __restrict__ C,
                int M, int N, int K) {
  __shared__ float As[32][65];  // [k][m], padded
  __shared__ float Bs[32][64];  // [k][n]
  const int nbm = M >> 6;
  const int bm = blockIdx.x % nbm;
  const int bn = blockIdx.x / nbm;
  const int tid = threadIdx.x;
  const int tr = tid >> 4, tc = tid & 15;
  double acc[4][4] = {};

  for (int kt = 0; kt < K; kt += 32) {
    {
      int arow = tid >> 3, acol = (tid & 7) * 4;
#pragma unroll
      for (int p = 0; p < 2; ++p) {
        int r = arow + p * 32;
        float4 v = *(const float4*)(A + (size_t)(bm * 64 + r) * K + kt + acol);
        As[acol + 0][r] = v.x; As[acol + 1][r] = v.y;
        As[acol + 2][r] = v.z; As[acol + 3][r] = v.w;
      }
      int brow = tid >> 4, bcol = (tid & 15) * 4;
#pragma unroll
      for (int p = 0; p < 2; ++p) {
        int r = brow + p * 16;
        float4 v = *(const float4*)(B + (size_t)(kt + r) * N + bn * 64 + bcol);
        *(float4*)(&Bs[r][bcol]) = v;
      }
    }
    __syncthreads();
#pragma unroll
    for (int k = 0; k < 32; ++k) {
      double a[4], b[4];
#pragma unroll
      for (int i = 0; i < 4; ++i) a[i] = (double)As[k][tr * 4 + i];
#pragma unroll
      for (int j = 0; j < 4; ++j) b[j] = (double)Bs[k][tc * 4 + j];
#pragma unroll
      for (int i = 0; i < 4; ++i)
#pragma unroll
        for (int j = 0; j < 4; ++j) acc[i][j] = fma(a[i], b[j], acc[i][j]);
    }
    __syncthreads();
  }
#pragma unroll
  for (int i = 0; i < 4; ++i) {
    int gm = bm * 64 + tr * 4 + i;
    int gn = bn * 64 + tc * 4;
    float4 o;
    o.x = (float)(acc[i][0] + (double)bias[gn + 0]);
    o.y = (float)(acc[i][1] + (double)bias[gn + 1]);
    o.z = (float)(acc[i][2] + (double)bias[gn + 2]);
    o.w = (float)(acc[i][3] + (double)bias[gn + 3]);
    *(float4*)(C + (size_t)gm * N + gn) = o;
  }
}

// ---------- transpose fp32 [K][N] -> fp32 [N][K] ----------
__global__ __launch_bounds__(256)
void transpose_f32(const float* __restrict__ W, float* __restrict__ WT,
                   int K, int N) {
  __shared__ float t[64][65];
  int k0 = blockIdx.x * 64;
  int n0 = blockIdx.y * 64;
  int tid = threadIdx.x;
  int r = tid >> 4, c4 = tid & 15;
#pragma unroll
  for (int i = 0; i < 4; ++i) {
    int row = r + i * 16;
    float4 v = *(const float4*)(W + (size_t)(k0 + row) * N + n0 + c4 * 4);
    t[row][c4 * 4 + 0] = v.x; t[row][c4 * 4 + 1] = v.y;
    t[row][c4 * 4 + 2] = v.z; t[row][c4 * 4 + 3] = v.w;
  }
  __syncthreads();
#pragma unroll
  for (int i = 0; i < 4; ++i) {
    int n = r + i * 16;
    float4 o;
    o.x = t[c4 * 4 + 0][n]; o.y = t[c4 * 4 + 1][n];
    o.z = t[c4 * 4 + 2][n]; o.w = t[c4 * 4 + 3][n];
    *(float4*)(WT + (size_t)(n0 + n) * K + k0 + c4 * 4) = o;
  }
}

// ---------- transpose fp32 [K][N] -> bf16 [N][K] ----------
__global__ __launch_bounds__(256)
void transpose_bf16(const float* __restrict__ W, unsigned short* __restrict__ WT,
                    int K, int N) {
  __shared__ float t[64][65];
  int k0 = blockIdx.x * 64;
  int n0 = blockIdx.y * 64;
  int tid = threadIdx.x;
  int r = tid >> 4, c4 = tid & 15;
#pragma unroll
  for (int i = 0; i < 4; ++i) {
    int row = r + i * 16;
    float4 v = *(const float4*)(W + (size_t)(k0 + row) * N + n0 + c4 * 4);
    t[row][c4 * 4 + 0] = v.x; t[row][c4 * 4 + 1] = v.y;
    t[row][c4 * 4 + 2] = v.z; t[row][c4 * 4 + 3] = v.w;
  }
  __syncthreads();
#pragma unroll
  for (int i = 0; i < 4; ++i) {
    int n = r + i * 16;
    ushort4 o;
    o.x = f2bf(t[c4 * 4 + 0][n]); o.y = f2bf(t[c4 * 4 + 1][n]);
    o.z = f2bf(t[c4 * 4 + 2][n]); o.w = f2bf(t[c4 * 4 + 3][n]);
    *(ushort4*)(WT + (size_t)(n0 + n) * K + k0 + c4 * 4) = o;
  }
}

// ---------- bf16 MFMA GEMM: C[M,N] = A[M,K] * BT[N,K]^T + bias ----------
// 128x128 tile, XOR-swizzled LDS, XCD-aware block swizzle, NT C-stores.
__global__ __launch_bounds__(256)
void gemm_bt_swap(const unsigned short* __restrict__ A, const unsigned short* __restrict__ BT,
                  const float* __restrict__ bias, float* __restrict__ C,
                  int M, int N, int K) {
  __shared__ unsigned short As[128 * 64];
  __shared__ unsigned short Bs[128 * 64];
  const int nbm = M >> 7;
  int idx = blockIdx.x;
  const int cpx = gridDim.x >> 3;
  idx = (idx & 7) * cpx + (idx >> 3);
  const int bm = idx % nbm;
  const int bn = idx / nbm;
  const int tid = threadIdx.x;
  const int lane = tid & 63;
  const int wr = (tid >> 6) >> 1;
  const int wc = (tid >> 6) & 1;

  f32x4 acc[4][4] = {};

  for (int kt = 0; kt < K; kt += 64) {
#pragma unroll
    for (int i = 0; i < 4; ++i) {
      int c = i * 256 + tid;
      int row = c >> 3, col8 = c & 7;
      int sw = col8 ^ (row & 7);
      short8 av = *(const short8*)(A + (size_t)(bm * 128 + row) * K + kt + col8 * 8);
      short8 bv = *(const short8*)(BT + (size_t)(bn * 128 + row) * K + kt + col8 * 8);
      *(short8*)(As + row * 64 + sw * 8) = av;
      *(short8*)(Bs + row * 64 + sw * 8) = bv;
    }
    __syncthreads();
#pragma unroll
    for (int kk = 0; kk < 64; kk += 32) {
      int kc = (kk + ((lane >> 4) << 3)) >> 3;
      short8 af[4], bfr[4];
#pragma unroll
      for (int mi = 0; mi < 4; ++mi) {
        int row = wr * 64 + mi * 16 + (lane & 15);
        af[mi] = *(const short8*)(As + row * 64 + ((kc ^ (row & 7)) << 3));
      }
#pragma unroll
      for (int ni = 0; ni < 4; ++ni) {
        int row = wc * 64 + ni * 16 + (lane & 15);
        bfr[ni] = *(const short8*)(Bs + row * 64 + ((kc ^ (row & 7)) << 3));
      }
#pragma unroll
      for (int mi = 0; mi < 4; ++mi)
#pragma unroll
        for (int ni = 0; ni < 4; ++ni)
          acc[mi][ni] = __builtin_amdgcn_mfma_f32_16x16x32_bf16(
              af[mi], bfr[ni], acc[mi][ni], 0, 0, 0);
    }
    __syncthreads();
  }

  const int cq = (lane >> 4) << 2;
  const int cn = lane & 15;
#pragma unroll
  for (int mi = 0; mi < 4; ++mi) {
#pragma unroll
    for (int ni = 0; ni < 4; ++ni) {
      int gn = bn * 128 + wc * 64 + ni * 16 + cn;
      float bv = bias[gn];
#pragma unroll
      for (int q = 0; q < 4; ++q) {
        int gm = bm * 128 + wr * 64 + mi * 16 + cq + q;
        int b = gm & (B_ - 1);
        int t = gm >> 5;
        // NT store: keep the 256 MB C stream from evicting A/B panels in L2
        __builtin_nontemporal_store(acc[mi][ni][q] + bv,
                                    &C[((size_t)b * T_ + t) * N + gn]);
      }
    }
  }
}

// ---------- RNN step v3: h_out = tanh(x + h_in @ Whh + bhh) ----------
// Grid 256 blocks x 512 threads; block owns 4 j-cols. W slice [4][1024] in
// LDS (16 KB, loaded once per step, 8x reuse). h read DIRECTLY from global
// (each element read exactly once per block -> no LDS round-trip).
// Thread (bt, ks): Rb=4 b-rows x Rj=4 j-cols, 64-way k-split (granules
// g = ks + 64i). Reduction: acc-halving pair-swap (17 f64 shfls vs 192).
__global__ __launch_bounds__(512)
void rnn_scan_step3(const float* __restrict__ h_in, const float* __restrict__ x,
                    int s, const float* __restrict__ WT,
                    const float* __restrict__ bhh, float* __restrict__ h_out,
                    unsigned short* __restrict__ hs_bf16) {
  __shared__ float wl[4 * 1024];  // 16 KB
  const int jbase = blockIdx.x * 4;
  const int tid = threadIdx.x;

  {  // stage WhhT rows [jbase, jbase+4): 1024 float4, linear (conflict-free)
    const float4* wsrc = (const float4*)(WT + (size_t)jbase * 1024);
#pragma unroll
    for (int p = 0; p < 2; ++p) {
      int i = tid + p * 512;
      ((float4*)wl)[i] = wsrc[i];
    }
  }
  __syncthreads();

  const int bt = tid >> 6;   // 8 b-tiles of 4 rows
  const int ks = tid & 63;   // k-split lane
  double acc[4][4];
#pragma unroll
  for (int bi = 0; bi < 4; ++bi)
#pragma unroll
    for (int ji = 0; ji < 4; ++ji) acc[bi][ji] = 0.;

#pragma unroll
  for (int i = 0; i < 4; ++i) {
    int g = ks + 64 * i;  // 16B granule (k = 4g..4g+3)
    float4 hv[4], wv[4];
#pragma unroll
    for (int bi = 0; bi < 4; ++bi)
      hv[bi] = *(const float4*)(h_in + (bt * 4 + bi) * 1024 + g * 4);
#pragma unroll
    for (int ji = 0; ji < 4; ++ji)
      wv[ji] = *(const float4*)(wl + ji * 1024 + g * 4);
#pragma unroll
    for (int bi = 0; bi < 4; ++bi)
#pragma unroll
      for (int ji = 0; ji < 4; ++ji) {
        acc[bi][ji] = fma((double)hv[bi].x, (double)wv[ji].x, acc[bi][ji]);
        acc[bi][ji] = fma((double)hv[bi].y, (double)wv[ji].y, acc[bi][ji]);
        acc[bi][ji] = fma((double)hv[bi].z, (double)wv[ji].z, acc[bi][ji]);
        acc[bi][ji] = fma((double)hv[bi].w, (double)wv[ji].w, acc[bi][ji]);
      }
  }

  // acc-halving pair-swap reduction: flatten a = bi*4+ji.
  // After stage s (xor 2^s), live accs halve; lane bit s selects which half
  // it owns. Final owned index a = 8*b0 + 4*b1 + 2*b2 + 1*b3.
  double r8[8], r4[4], r2[2], r1;
  const int l = ks;
#pragma unroll
  for (int a = 0; a < 8; ++a) {
    double send = (l & 1) ? acc[a >> 2][a & 3] : acc[(a + 8) >> 2][(a + 8) & 3];
    double mine = (l & 1) ? acc[(a + 8) >> 2][(a + 8) & 3] : acc[a >> 2][a & 3];
    r8[a] = mine + __shfl_xor(send, 1);
  }
#pragma unroll
  for (int a = 0; a < 4; ++a) {
    double send = (l & 2) ? r8[a] : r8[a + 4];
    double mine = (l & 2) ? r8[a + 4] : r8[a];
    r4[a] = mine + __shfl_xor(send, 2);
  }
#pragma unroll
  for (int a = 0; a < 2; ++a) {
    double send = (l & 4) ? r4[a] : r4[a + 2];
    double mine = (l & 4) ? r4[a + 2] : r4[a];
    r2[a] = mine + __shfl_xor(send, 4);
  }
  {
    double send = (l & 8) ? r2[0] : r2[1];
    double mine = (l & 8) ? r2[1] : r2[0];
    r1 = mine + __shfl_xor(send, 8);
  }
  r1 += __shfl_xor(r1, 16);
  r1 += __shfl_xor(r1, 32);

  if (l < 16) {
    int a = 8 * (l & 1) + 4 * ((l >> 1) & 1) + 2 * ((l >> 2) & 1) + ((l >> 3) & 1);
    int gb = bt * 4 + (a >> 2);
    int gj = jbase + (a & 3);
    double v = r1 + (double)x[((size_t)gb * 64 + s) * 1024 + gj] + (double)bhh[gj];
    double h = tanh(v);
    h_out[gb * 1024 + gj] = (float)h;
    if (hs_bf16) hs_bf16[(size_t)s * (B_ * H_) + gb * 1024 + gj] = f2bf((float)h);
  }
}

// ---------- in-place log-softmax over rows of 32000 ----------
__global__ __launch_bounds__(256)
void log_softmax_rows(float* __restrict__ out) {
  float* row = out + (size_t)blockIdx.x * V_;
  const int tid = threadIdx.x;
  float m = -INFINITY, s = 0.f;
  for (int i = tid; i < V_ / 4; i += 256) {
    float4 v = *(const float4*)(row + i * 4);
    float mx = fmaxf(fmaxf(v.x, v.y), fmaxf(v.z, v.w));
    if (mx > m) { s *= __expf(m - mx); m = mx; }
    s += __expf(v.x - m) + __expf(v.y - m) + __expf(v.z - m) + __expf(v.w - m);
  }
#pragma unroll
  for (int o = 32; o; o >>= 1) {
    float mo = __shfl_xor(m, o);
    float so = __shfl_xor(s, o);
    float mn = fmaxf(m, mo);
    s = s * __expf(m - mn) + so * __expf(mo - mn);
    m = mn;
  }
  __shared__ float wm[4], wsv[4];
  int wv = tid >> 6;
  if ((tid & 63) == 0) { wm[wv] = m; wsv[wv] = s; }
  __syncthreads();
  float M = fmaxf(fmaxf(wm[0], wm[1]), fmaxf(wm[2], wm[3]));
  float Ssum = wsv[0] * __expf(wm[0] - M) + wsv[1] * __expf(wm[1] - M) +
               wsv[2] * __expf(wm[2] - M) + wsv[3] * __expf(wm[3] - M);
  float L = M + logf(Ssum);
  for (int i = tid; i < V_ / 4; i += 256) {
    float4 v = *(const float4*)(row + i * 4);
    v.x -= L; v.y -= L; v.z -= L; v.w -= L;
    *(float4*)(row + i * 4) = v;
  }
}

extern "C" void kernel_launch(void* const* d_in, const int* in_sizes, int n_in,
                              void* d_out, int out_size, void* d_ws, size_t ws_size,
                              hipStream_t stream) {
  const int*   src  = (const int*)  d_in[0];
  const int*   tgt  = (const int*)  d_in[1];
  const float* encE = (const float*)d_in[2];
  const float* decE = (const float*)d_in[3];
  const float* WihE = (const float*)d_in[4];
  const float* bihE = (const float*)d_in[5];
  const float* WhhE = (const float*)d_in[6];
  const float* bhhE = (const float*)d_in[7];
  const float* WihD = (const float*)d_in[8];
  const float* bihD = (const float*)d_in[9];
  const float* WhhD = (const float*)d_in[10];
  const float* bhhD = (const float*)d_in[11];
  const float* Wout = (const float*)d_in[12];
  const float* bout = (const float*)d_in[13];
  float* out = (float*)d_out;

  char* w = (char*)d_ws;
  float* x_e = (float*)w;                      w += (size_t)2048 * 1024 * 4;
  float* x_d = (float*)w;                      w += (size_t)2048 * 1024 * 4;
  float* h0  = (float*)w;                      w += 32 * 1024 * 4;
  float* h1  = (float*)w;                      w += 32 * 1024 * 4;
  float* WhhTe = (float*)w;                    w += (size_t)1024 * 1024 * 4;
  float* WhhTd = (float*)w;                    w += (size_t)1024 * 1024 * 4;
  float* AembF = (float*)w;                    w += (size_t)2048 * 512 * 4;
  unsigned short* hsb   = (unsigned short*)w;  w += (size_t)2048 * 1024 * 2;
  unsigned short* WoutT = (unsigned short*)w;  w += (size_t)V_ * 1024 * 2;

  // Input projections (f64-exact accumulate, f32 storage)
  gather_f32<<<B_ * S_, 128, 0, stream>>>(src, encE, AembF);
  dgemm_bias<<<(2048 / 64) * (H_ / 64), 256, 0, stream>>>(AembF, WihE, bihE, x_e,
                                                          2048, H_, E_);
  gather_f32<<<B_ * T_, 128, 0, stream>>>(tgt, decE, AembF);
  dgemm_bias<<<(2048 / 64) * (H_ / 64), 256, 0, stream>>>(AembF, WihD, bihD, x_d,
                                                          2048, H_, E_);

  // Pre-transpose recurrence weights: WhhT[j][k]
  transpose_f32<<<dim3(H_ / 64, H_ / 64), 256, 0, stream>>>(WhhE, WhhTe, H_, H_);
  transpose_f32<<<dim3(H_ / 64, H_ / 64), 256, 0, stream>>>(WhhD, WhhTd, H_, H_);

  // Encoder scan
  hipMemsetAsync(h0, 0, 32 * 1024 * 4, stream);
  float* hc = h0;
  float* hn = h1;
  for (int s = 0; s < S_; ++s) {
    rnn_scan_step3<<<256, 512, 0, stream>>>(hc, x_e, s, WhhTe, bhhE, hn,
                                            (unsigned short*)nullptr);
    float* tmp = hc; hc = hn; hn = tmp;
  }
  // Decoder scan, emitting hs rows (bf16, non-feedback) at row t*B + b
  for (int t = 0; t < T_; ++t) {
    rnn_scan_step3<<<256, 512, 0, stream>>>(hc, x_d, t, WhhTd, bhhD, hn, hsb);
    float* tmp = hc; hc = hn; hn = tmp;
  }

  // Logits: out[b][t][:] = hs[t*B+b] @ Wout + bout  (bf16 MFMA, raw logits)
  transpose_bf16<<<dim3(H_ / 64, V_ / 64), 256, 0, stream>>>(Wout, WoutT, H_, V_);
  gemm_bt_swap<<<(2048 / 128) * (V_ / 128), 256, 0, stream>>>(hsb, WoutT, bout, out,
                                                              2048, V_, H_);
  // In-place log-softmax
  log_softmax_rows<<<B_ * T_, 256, 0, stream>>>(out);
}